// Round 1
// baseline (125.969 us; speedup 1.0000x reference)
//
#include <hip/hip_runtime.h>
#include <hip/hip_bf16.h>

// B=4, L=1024, H=8, E=D=64
#define NB 4
#define NL 1024
#define NH 8
#define NE 64

typedef __bf16 bf16x8_t __attribute__((ext_vector_type(8)));
typedef __bf16 bf16x4_t __attribute__((ext_vector_type(4)));
typedef float f32x4_t __attribute__((ext_vector_type(4)));

// LDS element index with XOR swizzle: tile is [rows][64] bf16 (128B rows).
// byte ^= ((row&7)<<4)  ==  elem ^= ((row&7)<<3). Keeps 8/4-elem alignment.
__device__ __forceinline__ int lidx(int row, int col) {
    return (row << 6) + (col ^ ((row & 7) << 3));
}

// ---------------------------------------------------------------------------
// Attention: one workgroup (4 waves, 256 thr) owns a 64-row tile of one (b,h).
// Pass A: QK^T -> row sums (no max subtraction: scaled logits ~N(0,1), safe).
// Pass B: recompute QK^T -> normalized series writes + PV via LDS P tile.
// Strict-upper causal tiles zero-filled by the same workgroup.
// ---------------------------------------------------------------------------
__global__ __launch_bounds__(256) void attn_kernel(
    const float* __restrict__ Qg, const float* __restrict__ Kg,
    const float* __restrict__ Vg, float* __restrict__ outV,
    float* __restrict__ outSer)
{
    __shared__ __bf16 Kt[64 * 64];      // K tile [row=k-row][e] (also Q staging)
    __shared__ __bf16 Vt[64 * 64];      // V tile transposed [d][j]
    __shared__ __bf16 Pt[4][16 * 64];   // per-wave P tile [i_local][j]

    const int wg = blockIdx.x;
    const int t  = wg & 15;              // row tile index
    const int p  = wg >> 4;              // b*8 + h
    const int h  = p & 7;
    const int b  = p >> 3;
    const int tid  = threadIdx.x;
    const int lane = tid & 63;
    const int wave = tid >> 6;
    const int l16  = lane & 15;
    const int lq   = lane >> 4;

    const int r0 = t << 6;
    const int rowstride = NH * NE;       // 512 floats per (b,l) row
    const float* Qb = Qg + ((size_t)b * NL) * rowstride + (size_t)h * NE;
    const float* Kb = Kg + ((size_t)b * NL) * rowstride + (size_t)h * NE;
    const float* Vb = Vg + ((size_t)b * NL) * rowstride + (size_t)h * NE;
    float* ser = outSer + ((size_t)(b * NH + h) << 20);

    // stage a 64x64 f32 tile -> bf16 LDS (row-major, swizzled)
    auto stageQK = [&](const float* src, int rowbase, __bf16* dst) {
        #pragma unroll
        for (int it = 0; it < 4; ++it) {
            int g   = tid + (it << 8);       // 0..1023 float4 granules
            int row = g >> 4;
            int c4  = (g & 15) << 2;
            float4 v = *(const float4*)(src + (size_t)(rowbase + row) * rowstride + c4);
            bf16x4_t w;
            w[0] = (__bf16)v.x; w[1] = (__bf16)v.y;
            w[2] = (__bf16)v.z; w[3] = (__bf16)v.w;
            *(bf16x4_t*)(dst + lidx(row, c4)) = w;
        }
    };
    // stage V 64x64 transposed: Vt[d][j]
    auto stageV = [&](int rowbase) {
        #pragma unroll
        for (int it = 0; it < 4; ++it) {
            int g   = tid + (it << 8);
            int row = g >> 4;                // j
            int c4  = (g & 15) << 2;         // d
            float4 v = *(const float4*)(Vb + (size_t)(rowbase + row) * rowstride + c4);
            Vt[lidx(c4 + 0, row)] = (__bf16)v.x;
            Vt[lidx(c4 + 1, row)] = (__bf16)v.y;
            Vt[lidx(c4 + 2, row)] = (__bf16)v.z;
            Vt[lidx(c4 + 3, row)] = (__bf16)v.w;
        }
    };

    // ---- Q fragments (held in registers for both passes) ----
    stageQK(Qb, r0, Kt);
    __syncthreads();
    bf16x8_t qf0, qf1;
    {
        int row = (wave << 4) + l16;
        qf0 = *(bf16x8_t*)(Kt + lidx(row, lq << 3));
        qf1 = *(bf16x8_t*)(Kt + lidx(row, 32 + (lq << 3)));
    }

    const float scale = 0.125f;                       // 1/sqrt(64)
    const int ibase = r0 + (wave << 4) + (lq << 2);   // +r = global query row

    // ================= pass A: row sums =================
    float psum[4] = {0.f, 0.f, 0.f, 0.f};
    for (int ct = 0; ct <= t; ++ct) {
        __syncthreads();
        stageQK(Kb, ct << 6, Kt);
        __syncthreads();
        #pragma unroll
        for (int ns = 0; ns < 4; ++ns) {
            int krow = (ns << 4) + l16;
            bf16x8_t k0 = *(bf16x8_t*)(Kt + lidx(krow, lq << 3));
            bf16x8_t k1 = *(bf16x8_t*)(Kt + lidx(krow, 32 + (lq << 3)));
            f32x4_t acc = {0.f, 0.f, 0.f, 0.f};
            acc = __builtin_amdgcn_mfma_f32_16x16x32_bf16(qf0, k0, acc, 0, 0, 0);
            acc = __builtin_amdgcn_mfma_f32_16x16x32_bf16(qf1, k1, acc, 0, 0, 0);
            int jg = (ct << 6) + (ns << 4) + l16;
            #pragma unroll
            for (int r = 0; r < 4; ++r) {
                float e = (jg <= ibase + r) ? __expf(acc[r] * scale) : 0.f;
                psum[r] += e;
            }
        }
    }

    float rinv[4];
    #pragma unroll
    for (int r = 0; r < 4; ++r) {
        float s = psum[r];
        s += __shfl_xor(s, 1);
        s += __shfl_xor(s, 2);
        s += __shfl_xor(s, 4);
        s += __shfl_xor(s, 8);
        rinv[r] = 1.f / s;
    }

    // ================= pass B: series + PV =================
    f32x4_t accO[4];
    #pragma unroll
    for (int ns = 0; ns < 4; ++ns) accO[ns] = (f32x4_t){0.f, 0.f, 0.f, 0.f};

    __bf16* Pw = Pt[wave];

    for (int ct = 0; ct <= t; ++ct) {
        __syncthreads();
        stageQK(Kb, ct << 6, Kt);
        stageV(ct << 6);
        __syncthreads();
        #pragma unroll
        for (int ns = 0; ns < 4; ++ns) {
            int krow = (ns << 4) + l16;
            bf16x8_t k0 = *(bf16x8_t*)(Kt + lidx(krow, lq << 3));
            bf16x8_t k1 = *(bf16x8_t*)(Kt + lidx(krow, 32 + (lq << 3)));
            f32x4_t acc = {0.f, 0.f, 0.f, 0.f};
            acc = __builtin_amdgcn_mfma_f32_16x16x32_bf16(qf0, k0, acc, 0, 0, 0);
            acc = __builtin_amdgcn_mfma_f32_16x16x32_bf16(qf1, k1, acc, 0, 0, 0);
            int jg = (ct << 6) + (ns << 4) + l16;
            #pragma unroll
            for (int r = 0; r < 4; ++r) {
                float e  = (jg <= ibase + r) ? __expf(acc[r] * scale) : 0.f;
                float pv = e * rinv[r];
                int il = (wave << 4) + (lq << 2) + r;     // local row 0..63
                ser[(size_t)(r0 + il) * NL + jg] = pv;
                Pw[lidx((lq << 2) + r, (ns << 4) + l16)] = (__bf16)pv;
            }
        }
        // PV: O += P * V   (A = P row-major, B^T = Vt row-major; same-wave LDS,
        // no barrier needed)
        #pragma unroll
        for (int ks = 0; ks < 2; ++ks) {
            bf16x8_t pa = *(bf16x8_t*)(Pw + lidx(l16, (ks << 5) + (lq << 3)));
            #pragma unroll
            for (int ns = 0; ns < 4; ++ns) {
                bf16x8_t vb = *(bf16x8_t*)(Vt + lidx((ns << 4) + l16, (ks << 5) + (lq << 3)));
                accO[ns] = __builtin_amdgcn_mfma_f32_16x16x32_bf16(pa, vb, accO[ns], 0, 0, 0);
            }
        }
    }

    // ---- write V output [B,L,H,D] ----
    #pragma unroll
    for (int ns = 0; ns < 4; ++ns) {
        #pragma unroll
        for (int r = 0; r < 4; ++r) {
            int ig = ibase + r;
            int d  = (ns << 4) + l16;
            outV[((size_t)b * NL + ig) * rowstride + (size_t)h * NE + d] = accO[ns][r];
        }
    }

    // ---- zero-fill fully-masked column tiles of series ----
    const int c0 = (t + 1) << 6;
    if (c0 < NL) {
        int col = c0 + (tid << 2);
        if (col < NL) {
            float4 z = {0.f, 0.f, 0.f, 0.f};
            for (int row = 0; row < 64; ++row) {
                *(float4*)(ser + (size_t)(r0 + row) * NL + col) = z;
            }
        }
    }
}

// ---------------------------------------------------------------------------
// Prior + sigma_out: one block per (b,h,i) row; 256 thr x 4 cols, float4 I/O.
// ---------------------------------------------------------------------------
__global__ __launch_bounds__(256) void prior_kernel(
    const float* __restrict__ sigma, float* __restrict__ outP,
    float* __restrict__ outSg)
{
    const int wg = blockIdx.x;           // 0..32767 = (b*8+h)*1024 + i
    const int i  = wg & (NL - 1);
    const int ph = wg >> 10;
    const int b  = ph >> 3;
    const int h  = ph & 7;
    const int tid = threadIdx.x;

    const float s   = sigma[((size_t)b * NL + i) * NH + h];
    const float sig = 1.f / (1.f + __expf(-5.f * s)) + 1e-5f;
    // 3^sig - 1 = expm1(sig*ln3): expm1 avoids catastrophic cancellation at sig~1e-5
    const float sg  = expm1f(sig * 1.0986122886681098f);
    const float cst = 0.3989422804014327f / sg;      // 1/(sqrt(2pi)*sg)
    const float ni  = -0.5f / (sg * sg);

    const size_t base = ((size_t)ph << 20) + ((size_t)i << 10);
    const int j0 = tid << 2;
    const float fd = (float)(i - j0);
    float4 pr;
    pr.x = cst * __expf(fd * fd * ni);
    float f1 = fd - 1.f; pr.y = cst * __expf(f1 * f1 * ni);
    float f2 = fd - 2.f; pr.z = cst * __expf(f2 * f2 * ni);
    float f3 = fd - 3.f; pr.w = cst * __expf(f3 * f3 * ni);
    *(float4*)(outP + base + j0) = pr;
    float4 sgv = {sg, sg, sg, sg};
    *(float4*)(outSg + base + j0) = sgv;
}

extern "C" void kernel_launch(void* const* d_in, const int* in_sizes, int n_in,
                              void* d_out, int out_size, void* d_ws, size_t ws_size,
                              hipStream_t stream) {
    const float* Q  = (const float*)d_in[0];
    const float* K  = (const float*)d_in[1];
    const float* V  = (const float*)d_in[2];
    const float* Sg = (const float*)d_in[3];

    float* out      = (float*)d_out;
    float* outV     = out;                      // [4,1024,8,64]   = 2,097,152
    float* outSer   = out + 2097152;            // [4,8,1024,1024] = 33,554,432
    float* outPrior = out + 35651584;           // [4,8,1024,1024]
    float* outSig   = out + 69206016;           // [4,8,1024,1024]

    hipLaunchKernelGGL(prior_kernel, dim3(NB * NH * NL), dim3(256), 0, stream,
                       Sg, outPrior, outSig);
    hipLaunchKernelGGL(attn_kernel, dim3(NB * NH * 16), dim3(256), 0, stream,
                       Q, K, V, outV, outSer);
}